// Round 1
// baseline (135.576 us; speedup 1.0000x reference)
//
#include <hip/hip_runtime.h>
#include <hip/hip_bf16.h>

typedef unsigned short u16;
typedef __attribute__((ext_vector_type(8))) short short8;
typedef __attribute__((ext_vector_type(4))) float floatx4;

#define NB 32
#define NCI 256
#define NCO 256
#define NW 4096
#define NK 5

#define BM 128
#define BN 128
#define WROW 168            // elems per W2 row: 5*32 + 8 pad  (336 B)
#define WROWB 336
#define XROWB 80            // bytes per Xs row: 32*2 + 16 pad
#define XTROWS 4100         // 4096 + 2+2 halo
#define W2_BYTES (8*256*WROW*2)           // 688128
#define XT_BYTES ((size_t)NB*XTROWS*256*2) // 67174400

#define WTILE_B (BM*WROWB)   // 43008
#define XTILE_B (132*XROWB)  // 10560

// ---------------- pre-kernels ----------------

__global__ void wprep(const float* __restrict__ wgt, u16* __restrict__ W2) {
    int i = blockIdx.x * 256 + threadIdx.x;         // over co*1280 + ci*5 + k
    if (i >= NCO * NCI * NK) return;
    int k  = i % NK;
    int ci = (i / NK) % NCI;
    int co = i / (NCI * NK);
    __hip_bfloat16 h = __float2bfloat16(wgt[i]);
    W2[((size_t)(ci >> 5) * 256 + co) * WROW + k * 32 + (ci & 31)] =
        *reinterpret_cast<u16*>(&h);
}

__global__ void xprep(const float* __restrict__ x, u16* __restrict__ xT) {
    // grid (128 w-tiles, 8 ci-tiles, 32 b); block 256 = 32x8; 32x32 transpose tile
    int wt = blockIdx.x, ct = blockIdx.y, b = blockIdx.z;
    int tx = threadIdx.x & 31, ty = threadIdx.x >> 5;
    __shared__ float sh[32][33];
    int w0 = wt * 32, c0 = ct * 32;
    const float* xb = x + ((size_t)b * NCI + c0) * NW + w0;
#pragma unroll
    for (int r = 0; r < 4; r++)
        sh[ty + 8 * r][tx] = xb[(size_t)(ty + 8 * r) * NW + tx];
    __syncthreads();
    u16* dst = xT + ((size_t)b * XTROWS + (w0 + 2)) * 256 + c0;
#pragma unroll
    for (int r = 0; r < 4; r++) {
        __hip_bfloat16 h = __float2bfloat16(sh[tx][ty + 8 * r]);
        dst[(size_t)(ty + 8 * r) * 256 + tx] = *reinterpret_cast<u16*>(&h);
    }
}

__global__ void xzero(u16* __restrict__ xT) {
    int i = blockIdx.x * 256 + threadIdx.x;          // 32 b * 4 rows * 256 ci
    if (i >= 32 * 4 * 256) return;
    int ci = i & 255, r = (i >> 8) & 3, b = i >> 10;
    int row = (r < 2) ? r : (4096 + r);              // rows 0,1,4098,4099
    xT[((size_t)b * XTROWS + row) * 256 + ci] = 0;
}

// ---------------- helpers ----------------

__device__ __forceinline__ void gload_lds16(const void* gsrc, void* ldst) {
    __builtin_amdgcn_global_load_lds(
        (const __attribute__((address_space(1))) unsigned int*)gsrc,
        (__attribute__((address_space(3))) unsigned int*)ldst, 16, 0, 0);
}

// ---------------- main MFMA conv ----------------

__global__ __launch_bounds__(256, 3)
void conv_mfma(const u16* __restrict__ W2, const u16* __restrict__ xT,
               const float* __restrict__ bias, float* __restrict__ out) {
    __shared__ __align__(16) char smem[WTILE_B + XTILE_B];
    char* wlds = smem;
    char* xlds = smem + WTILE_B;

    int bid  = blockIdx.x;
    int cot  = bid & 1;            // co-tile (0/1)
    int wt   = (bid >> 1) & 31;    // w-tile
    int b    = bid >> 6;           // batch
    int tid  = threadIdx.x;
    int lane = tid & 63, wave = tid >> 6;
    int wm   = wave >> 1, wn = wave & 1;   // 2x2 wave grid, 64x64 each
    int mrow = lane & 15, g = lane >> 4;

    int co0 = cot * BM;
    int w0  = wt * BN;

    floatx4 acc[4][4];
#pragma unroll
    for (int mi = 0; mi < 4; mi++)
#pragma unroll
        for (int ni = 0; ni < 4; ni++)
            acc[mi][ni] = (floatx4){0.f, 0.f, 0.f, 0.f};

    const u16* xsrc_base = xT + ((size_t)b * XTROWS + w0) * 256;

    for (int cb = 0; cb < 8; cb++) {
        // ---- stage weights: byte-exact linear copy global->LDS (42 KB)
        const char* wsrc = (const char*)W2 + ((size_t)cb * 256 + co0) * WROWB;
        for (int idx = wave; idx < WTILE_B / 1024; idx += 4)
            gload_lds16(wsrc + idx * 1024 + lane * 16, wlds + idx * 1024);

        // ---- stage X: reg-stage into padded 80B rows (132 rows x 64B data)
        {
#pragma unroll
            for (int rep = 0; rep < 2; rep++) {
                int cc  = tid + rep * 256;           // chunk 0..511
                int row = cc >> 2, sub = cc & 3;
                const char* s =
                    (const char*)(xsrc_base + (size_t)row * 256 + cb * 32) + sub * 16;
                int4 v = *(const int4*)s;
                *(int4*)(xlds + row * XROWB + sub * 16) = v;
            }
            if (tid < 16) {
                int cc  = tid + 512;                 // chunks 512..527
                int row = cc >> 2, sub = cc & 3;
                const char* s =
                    (const char*)(xsrc_base + (size_t)row * 256 + cb * 32) + sub * 16;
                int4 v = *(const int4*)s;
                *(int4*)(xlds + row * XROWB + sub * 16) = v;
            }
        }
        __syncthreads();

        // ---- compute: 5 taps x (4m x 4n) MFMA, K=32 per ci-block
#pragma unroll
        for (int t = 0; t < NK; t++) {
            short8 af[4], bf[4];
#pragma unroll
            for (int mi = 0; mi < 4; mi++)
                af[mi] = *(const short8*)(wlds +
                         (wm * 64 + mi * 16 + mrow) * WROWB + t * 64 + g * 16);
#pragma unroll
            for (int ni = 0; ni < 4; ni++)
                bf[ni] = *(const short8*)(xlds +
                         (wn * 64 + ni * 16 + mrow + t) * XROWB + g * 16);
#pragma unroll
            for (int mi = 0; mi < 4; mi++)
#pragma unroll
                for (int ni = 0; ni < 4; ni++)
                    acc[mi][ni] = __builtin_amdgcn_mfma_f32_16x16x32_bf16(
                        af[mi], bf[ni], acc[mi][ni], 0, 0, 0);
        }
        __syncthreads();
    }

    // ---- epilogue: C/D layout col=lane&15, row=g*4+reg (m89-verified)
#pragma unroll
    for (int mi = 0; mi < 4; mi++) {
        int cobase = co0 + wm * 64 + mi * 16 + g * 4;
        float bv[4];
#pragma unroll
        for (int r = 0; r < 4; r++) bv[r] = bias[cobase + r];
#pragma unroll
        for (int ni = 0; ni < 4; ni++) {
            int col = w0 + wn * 64 + ni * 16 + mrow;
#pragma unroll
            for (int r = 0; r < 4; r++)
                out[((size_t)b * NCO + cobase + r) * NW + col] =
                    acc[mi][ni][r] + bv[r];
        }
    }
}

// ---------------- fallback (ws too small): naive fp32 ----------------

__global__ void conv_naive(const float* __restrict__ x, const float* __restrict__ wgt,
                           const float* __restrict__ bias, float* __restrict__ out) {
    int w  = blockIdx.x * 256 + threadIdx.x;
    int co = blockIdx.y;
    int b  = blockIdx.z;
    float acc = bias[co];
    for (int ci = 0; ci < NCI; ci++) {
        const float* xr = x + ((size_t)b * NCI + ci) * NW;
        const float* wr = wgt + ((size_t)co * NCI + ci) * NK;
#pragma unroll
        for (int k = 0; k < NK; k++) {
            int wi = w + k - 2;
            if (wi >= 0 && wi < NW) acc += xr[wi] * wr[k];
        }
    }
    out[((size_t)b * NCO + co) * NW + w] = acc;
}

// ---------------- launch ----------------

extern "C" void kernel_launch(void* const* d_in, const int* in_sizes, int n_in,
                              void* d_out, int out_size, void* d_ws, size_t ws_size,
                              hipStream_t stream) {
    const float* x    = (const float*)d_in[0];
    const float* wgt  = (const float*)d_in[1];
    const float* bias = (const float*)d_in[2];
    float* out        = (float*)d_out;

    size_t need = (size_t)W2_BYTES + XT_BYTES;
    if (ws_size < need) {
        conv_naive<<<dim3(NW / 256, NCO, NB), 256, 0, stream>>>(x, wgt, bias, out);
        return;
    }

    u16* W2 = (u16*)d_ws;
    u16* xT = (u16*)((char*)d_ws + W2_BYTES);

    wprep<<<(NCO * NCI * NK + 255) / 256, 256, 0, stream>>>(wgt, W2);
    xprep<<<dim3(NW / 32, NCI / 32, NB), 256, 0, stream>>>(x, xT);
    xzero<<<(32 * 4 * 256 + 255) / 256, 256, 0, stream>>>(xT);
    conv_mfma<<<2048, 256, 0, stream>>>(W2, xT, bias, out);
}